// Round 2
// baseline (901.644 us; speedup 1.0000x reference)
//
#include <hip/hip_runtime.h>

// EntityMarker: inclusive span-mean over sequence_output rows.
//   sequence_output: [B, L, H] fp32, B=128, L=2048, H=768
//   entity_positions: [B, 4] int32 on device (h_start, h_end, t_start, t_end)
//   out: head [B,H] then tail [B,H], fp32, concatenated flat.
//
// Two-pass deterministic reduction (no atomics, no output memset):
//   Pass 1: 2B spans x CHUNKS chunks; each block sums its chunk's rows,
//           pre-scales by 1/count, writes a [H] partial to d_ws.
//           192 threads = one float4 column each -> coalesced 3 KB row reads.
//           Empty chunks write zeros (deterministic pass-2 input).
//   Pass 2: one thread per output element, sums CHUNKS partials, writes d_out.
// Fallback: if ws_size can't hold the partials, use the verified atomic path.

#define L_SEQ  2048
#define H_DIM  768
#define CHUNKS 32
#define TPB    192   // H_DIM/4 float4 columns, 3 waves

__device__ __forceinline__ void span_bounds(const int* __restrict__ pos,
                                            int b, int ent,
                                            int& r0, int& r1, int& len,
                                            int chunk, int nchunks)
{
    const int p0 = pos[b * 4 + 2 * ent + 0];
    const int p1 = pos[b * 4 + 2 * ent + 1];
    const int s  = min(max(p0, 0), L_SEQ - 1);
    const int e  = max(s, min(p1, L_SEQ - 1));
    len = e - s + 1;                       // >= 1
    const int per = (len + nchunks - 1) / nchunks;
    r0 = s + chunk * per;
    r1 = min(r0 + per, e + 1);
}

__device__ __forceinline__ float4 chunk_sum(const float* __restrict__ seq,
                                            int b, int col, int r0, int r1)
{
    const float4* __restrict__ base =
        (const float4*)(seq + (size_t)b * L_SEQ * H_DIM);
    float4 a0 = make_float4(0.f, 0.f, 0.f, 0.f);
    float4 a1 = a0, a2 = a0, a3 = a0;
    int r = r0;
    for (; r + 3 < r1; r += 4) {           // 4 outstanding loads / thread
        float4 v0 = base[(size_t)(r + 0) * (H_DIM / 4) + col];
        float4 v1 = base[(size_t)(r + 1) * (H_DIM / 4) + col];
        float4 v2 = base[(size_t)(r + 2) * (H_DIM / 4) + col];
        float4 v3 = base[(size_t)(r + 3) * (H_DIM / 4) + col];
        a0.x += v0.x; a0.y += v0.y; a0.z += v0.z; a0.w += v0.w;
        a1.x += v1.x; a1.y += v1.y; a1.z += v1.z; a1.w += v1.w;
        a2.x += v2.x; a2.y += v2.y; a2.z += v2.z; a2.w += v2.w;
        a3.x += v3.x; a3.y += v3.y; a3.z += v3.z; a3.w += v3.w;
    }
    for (; r < r1; ++r) {
        float4 v0 = base[(size_t)r * (H_DIM / 4) + col];
        a0.x += v0.x; a0.y += v0.y; a0.z += v0.z; a0.w += v0.w;
    }
    return make_float4((a0.x + a1.x) + (a2.x + a3.x),
                       (a0.y + a1.y) + (a2.y + a3.y),
                       (a0.z + a1.z) + (a2.z + a3.z),
                       (a0.w + a1.w) + (a2.w + a3.w));
}

// ---------- two-pass path ----------

__global__ __launch_bounds__(TPB) void pass1_partials(
    const float* __restrict__ seq,
    const int*   __restrict__ pos,
    float*       __restrict__ ws,    // [2B * CHUNKS, H]
    int B)
{
    const int blk   = blockIdx.x;
    const int chunk = blk % CHUNKS;
    const int span  = blk / CHUNKS;       // 0 .. 2B-1
    const int ent   = span & 1;
    const int b     = span >> 1;

    int r0, r1, len;
    span_bounds(pos, b, ent, r0, r1, len, chunk, CHUNKS);

    const int col = threadIdx.x;
    float4 sum = make_float4(0.f, 0.f, 0.f, 0.f);
    if (r0 < r1) {
        sum = chunk_sum(seq, b, col, r0, r1);
        const float inv = 1.0f / (float)len;
        sum.x *= inv; sum.y *= inv; sum.z *= inv; sum.w *= inv;
    }
    ((float4*)ws)[(size_t)blk * (H_DIM / 4) + col] = sum;
}

__global__ __launch_bounds__(256) void pass2_reduce(
    const float* __restrict__ ws,    // [2B * CHUNKS, H]
    float*       __restrict__ out,   // [2, B, H]
    int B)
{
    const int idx = blockIdx.x * 256 + threadIdx.x;   // 0 .. 2B*H-1
    if (idx >= 2 * B * H_DIM) return;
    const int span = idx / H_DIM;
    const int h    = idx - span * H_DIM;
    const int ent  = span & 1;
    const int b    = span >> 1;

    const float* __restrict__ p = ws + (size_t)span * CHUNKS * H_DIM + h;
    float acc = 0.f;
#pragma unroll
    for (int c = 0; c < CHUNKS; ++c) acc += p[(size_t)c * H_DIM];

    out[(size_t)ent * B * H_DIM + (size_t)b * H_DIM + h] = acc;
}

// ---------- fallback atomic path (verified in round 1) ----------

__global__ __launch_bounds__(TPB) void atomic_span_mean(
    const float* __restrict__ seq,
    const int*   __restrict__ pos,
    float*       __restrict__ out,
    int B)
{
    const int blk   = blockIdx.x;
    const int chunk = blk % 16;
    const int span  = blk / 16;
    const int ent   = span & 1;
    const int b     = span >> 1;

    int r0, r1, len;
    span_bounds(pos, b, ent, r0, r1, len, chunk, 16);
    if (r0 >= r1) return;

    const int col = threadIdx.x;
    float4 sum = chunk_sum(seq, b, col, r0, r1);
    const float inv = 1.0f / (float)len;
    float* o = out + (size_t)ent * B * H_DIM + (size_t)b * H_DIM + col * 4;
    atomicAdd(o + 0, sum.x * inv);
    atomicAdd(o + 1, sum.y * inv);
    atomicAdd(o + 2, sum.z * inv);
    atomicAdd(o + 3, sum.w * inv);
}

extern "C" void kernel_launch(void* const* d_in, const int* in_sizes, int n_in,
                              void* d_out, int out_size, void* d_ws, size_t ws_size,
                              hipStream_t stream) {
    const float* seq = (const float*)d_in[0];
    const int*   pos = (const int*)d_in[1];
    float*       out = (float*)d_out;

    const int B = in_sizes[1] / 4;        // 128

    const size_t ws_needed = (size_t)2 * B * CHUNKS * H_DIM * sizeof(float);
    if (ws_size >= ws_needed) {
        float* ws = (float*)d_ws;
        pass1_partials<<<2 * B * CHUNKS, TPB, 0, stream>>>(seq, pos, ws, B);
        const int n_out = 2 * B * H_DIM;
        pass2_reduce<<<(n_out + 255) / 256, 256, 0, stream>>>(ws, out, B);
    } else {
        hipMemsetAsync(d_out, 0, (size_t)out_size * sizeof(float), stream);
        atomic_span_mean<<<2 * B * 16, TPB, 0, stream>>>(seq, pos, out, B);
    }
}